// Round 2
// baseline (16667.947 us; speedup 1.0000x reference)
//
#include <hip/hip_runtime.h>

#define T_STEPS 4096
#define RSIZE   2048
#define N_IN    8
#define N_OUT   4
#define NWG     256
#define NT      256                  // 4 waves per WG (waves are fully independent now)
#define LIN_STRIDE  (RSIZE + N_IN)   // 2056 — readout weight row stride
#define SENTINEL    0x7FC00000u      // qNaN bits; recurrence never produces it

typedef float v4 __attribute__((ext_vector_type(4)));
typedef float v2 __attribute__((ext_vector_type(2)));

// d_ws: states [T][R] float. Row 0 zeros, rows 1.. sentinel. Data IS the flag.

__global__ __launch_bounds__(256) void init_kernel(v4* __restrict__ states4) {
    int idx = blockIdx.x * 256 + threadIdx.x;        // 0 .. T*R/4-1
    const float s = __uint_as_float(SENTINEL);
    v4 v = (idx < RSIZE / 4) ? (v4){0.f, 0.f, 0.f, 0.f} : (v4){s, s, s, s};
    states4[idx] = v;
}

__device__ __forceinline__ float dot4(v4 a, v4 b) {
    float s = a.x * b.x;
    s = fmaf(a.y, b.y, s);
    s = fmaf(a.z, b.z, s);
    s = fmaf(a.w, b.w, s);
    return s;
}

// Latency-bound recurrence: no LDS, no __syncthreads. Each wave polls the 32
// columns it needs (8 x volatile dwordx4, covering the full 8 KB row across
// its 64 lanes) and dots straight out of the polled registers. Removing the
// LDS round-trip + 2 barriers shortens the serial per-step chain; waves no
// longer wait on their workgroup siblings' poll completion.

__global__ __launch_bounds__(NT, 1) void reservoir_kernel(
    const float* __restrict__ W,        // [R][R]
    const float* __restrict__ Win,      // [R][8]
    const float* __restrict__ Wfb,      // [R][4]
    const float* __restrict__ inputs,   // [T][8]
    const float* __restrict__ outputs,  // [T][4]
    const float* __restrict__ noise,    // [T][R]
    float* __restrict__ states)         // [T][R]
{
    const int g    = blockIdx.x;
    const int t    = threadIdx.x;
    const int lane = t & 63;
    const int wv   = t >> 6;            // wave in WG: 0..3
    const int wid  = g * 4 + wv;        // global wave: 0..1023
    const int r0   = wid * 2;           // this wave's 2 rows

    // ---- W into NAMED registers: 2 rows x 32 cols/lane, cols = j*512 + lane*8 + k ----
    const float* wr0 = W + (size_t)r0 * RSIZE + lane * 8;
    const float* wr1 = wr0 + RSIZE;
    v4 w000 = *(const v4*)(wr0 +    0), w001 = *(const v4*)(wr0 +    4);
    v4 w010 = *(const v4*)(wr0 +  512), w011 = *(const v4*)(wr0 +  516);
    v4 w020 = *(const v4*)(wr0 + 1024), w021 = *(const v4*)(wr0 + 1028);
    v4 w030 = *(const v4*)(wr0 + 1536), w031 = *(const v4*)(wr0 + 1540);
    v4 w100 = *(const v4*)(wr1 +    0), w101 = *(const v4*)(wr1 +    4);
    v4 w110 = *(const v4*)(wr1 +  512), w111 = *(const v4*)(wr1 +  516);
    v4 w120 = *(const v4*)(wr1 + 1024), w121 = *(const v4*)(wr1 + 1028);
    v4 w130 = *(const v4*)(wr1 + 1536), w131 = *(const v4*)(wr1 + 1540);
    // Pin W: opaque to the optimizer so the loads can't sink into the time loop.
    asm volatile("" : "+v"(w000), "+v"(w001), "+v"(w010), "+v"(w011));
    asm volatile("" : "+v"(w020), "+v"(w021), "+v"(w030), "+v"(w031));
    asm volatile("" : "+v"(w100), "+v"(w101), "+v"(w110), "+v"(w111));
    asm volatile("" : "+v"(w120), "+v"(w121), "+v"(w130), "+v"(w131));

    // ---- lanes 0,1 keep Win/Wfb for their row ----
    float win[N_IN] = {0}, wfb[N_OUT] = {0};
    if (lane < 2) {
        const int r = r0 + lane;
        #pragma unroll
        for (int j = 0; j < N_IN; ++j)  win[j] = Win[r * N_IN + j];
        #pragma unroll
        for (int k = 0; k < N_OUT; ++k) wfb[k] = Wfb[r * N_OUT + k];
    }

    const int li = lane * 2;   // v4 index of this lane's pair within a 512-col block

    for (int n = 1; n < T_STEPS; ++n) {
        // ---- pre-poll: terms that don't depend on x_{n-1} ----
        float pre = 0.0f, nz = 0.0f;
        if (lane < 2) {
            const int r = r0 + lane;
            nz = noise[(size_t)n * RSIZE + r];
            #pragma unroll
            for (int j = 0; j < N_IN; ++j)  pre = fmaf(win[j], inputs[n * N_IN + j], pre);
            #pragma unroll
            for (int k = 0; k < N_OUT; ++k) pre = fmaf(wfb[k], outputs[(n - 1) * N_OUT + k], pre);
        }

        // ---- poll ALL 32 cols this lane needs (8x volatile dwordx4) ----
        // Lane l covers cols {j*512 + l*8 .. +7} for j=0..3 — across 64 lanes
        // that's the full row, contiguous per block, so loads coalesce.
        const volatile v4* row = (const volatile v4*)(states + (size_t)(n - 1) * RSIZE);
        v4 x00, x01, x10, x11, x20, x21, x30, x31;
        #define OKV(v) ((__float_as_uint(v.x) != SENTINEL) & \
                        (__float_as_uint(v.y) != SENTINEL) & \
                        (__float_as_uint(v.z) != SENTINEL) & \
                        (__float_as_uint(v.w) != SENTINEL))
        for (;;) {
            x00 = row[  0 + li]; x01 = row[  0 + li + 1];
            x10 = row[128 + li]; x11 = row[128 + li + 1];
            x20 = row[256 + li]; x21 = row[256 + li + 1];
            x30 = row[384 + li]; x31 = row[384 + li + 1];
            bool ok = OKV(x00) & OKV(x01) & OKV(x10) & OKV(x11) &
                      OKV(x20) & OKV(x21) & OKV(x30) & OKV(x31);
            if (ok) break;
            __builtin_amdgcn_s_sleep(1);
        }
        #undef OKV

        // ---- 2-row dot over all 2048 cols, straight from polled registers ----
        // Same column order / add order as the LDS version: bit-identical.
        float acc0 = 0.0f, acc1 = 0.0f;
        acc0 += dot4(w000, x00) + dot4(w001, x01);
        acc1 += dot4(w100, x00) + dot4(w101, x01);
        acc0 += dot4(w010, x10) + dot4(w011, x11);
        acc1 += dot4(w110, x10) + dot4(w111, x11);
        acc0 += dot4(w020, x20) + dot4(w021, x21);
        acc1 += dot4(w120, x20) + dot4(w121, x21);
        acc0 += dot4(w030, x30) + dot4(w031, x31);
        acc1 += dot4(w130, x30) + dot4(w131, x31);

        // ---- 64-lane butterfly: every lane ends with both row totals ----
        #pragma unroll
        for (int m = 1; m < 64; m <<= 1) {
            acc0 += __shfl_xor(acc0, m, 64);
            acc1 += __shfl_xor(acc1, m, 64);
        }

        // ---- epilogue + publish: lanes 0,1 compute, lane 0 stores 8B once ----
        float xn = 0.0f;
        if (lane < 2) {
            float s = (lane == 0 ? acc0 : acc1) + pre;
            xn = tanhf(s) + nz;
        }
        float xn1 = __shfl(xn, 1, 64);
        if (lane == 0) {
            v2 st; st.x = xn; st.y = xn1;
            *(volatile v2*)(states + (size_t)n * RSIZE + r0) = st;
        }
        __builtin_amdgcn_s_waitcnt(0);   // flush publish promptly
    }
}

__global__ __launch_bounds__(256) void readout_kernel(
    const float* __restrict__ states,   // [T][R]
    const float* __restrict__ inputs,   // [T][8]
    const float* __restrict__ lin_w,    // [4][2056]
    const float* __restrict__ lin_b,    // [4]
    float* __restrict__ out)            // [T][4]
{
    const int ti   = blockIdx.x;
    const int tid  = threadIdx.x;
    const int lane = tid & 63;
    const int wave = tid >> 6;
    const int c0   = tid * 8;

    const float* xp = states + (size_t)ti * RSIZE + c0;
    v4 xa = *(const v4*)xp;
    v4 xb = *(const v4*)(xp + 4);

    float acc[N_OUT];
    #pragma unroll
    for (int o = 0; o < N_OUT; ++o) {
        const float* lp = lin_w + (size_t)o * LIN_STRIDE + c0;
        v4 la = *(const v4*)lp;
        v4 lb = *(const v4*)(lp + 4);
        acc[o] = dot4(la, xa) + dot4(lb, xb);
    }

    #pragma unroll
    for (int m = 1; m < 64; m <<= 1) {
        #pragma unroll
        for (int o = 0; o < N_OUT; ++o) acc[o] += __shfl_xor(acc[o], m, 64);
    }

    __shared__ float red[4][N_OUT];
    if (lane == 0) {
        #pragma unroll
        for (int o = 0; o < N_OUT; ++o) red[wave][o] = acc[o];
    }
    __syncthreads();

    if (tid < N_OUT) {
        float s = red[0][tid] + red[1][tid] + red[2][tid] + red[3][tid] + lin_b[tid];
        if (ti > 0) {   // states_u row 0 is zero
            #pragma unroll
            for (int j = 0; j < N_IN; ++j)
                s = fmaf(lin_w[(size_t)tid * LIN_STRIDE + RSIZE + j],
                         inputs[ti * N_IN + j], s);
        }
        out[ti * N_OUT + tid] = s;
    }
}

extern "C" void kernel_launch(void* const* d_in, const int* in_sizes, int n_in,
                              void* d_out, int out_size, void* d_ws, size_t ws_size,
                              hipStream_t stream) {
    const float* inputs  = (const float*)d_in[0];
    const float* outputs = (const float*)d_in[1];
    const float* W       = (const float*)d_in[2];
    const float* Win     = (const float*)d_in[3];
    const float* Wfb     = (const float*)d_in[4];
    const float* lin_w   = (const float*)d_in[5];
    const float* lin_b   = (const float*)d_in[6];
    const float* noise   = (const float*)d_in[7];
    float* out = (float*)d_out;

    float* states = (float*)d_ws;

    hipLaunchKernelGGL(init_kernel, dim3((T_STEPS * RSIZE / 4) / 256), dim3(256), 0,
                       stream, (v4*)states);
    hipLaunchKernelGGL(reservoir_kernel, dim3(NWG), dim3(NT), 0, stream,
                       W, Win, Wfb, inputs, outputs, noise, states);
    hipLaunchKernelGGL(readout_kernel, dim3(T_STEPS), dim3(256), 0, stream,
                       states, inputs, lin_w, lin_b, out);
}

// Round 3
// 16208.089 us; speedup vs baseline: 1.0284x; 1.0284x over previous
//
#include <hip/hip_runtime.h>

#define T_STEPS 4096
#define RSIZE   2048
#define N_IN    8
#define N_OUT   4
#define LIN_STRIDE  (RSIZE + N_IN)   // 2056 — readout weight row stride
#define SENTINEL    0x7FC00000u      // qNaN bits; recurrence never produces it

typedef float v4 __attribute__((ext_vector_type(4)));

// d_ws: states [T][R] float. Row 0 zeros, rows 1.. sentinel. Data IS the flag.

__global__ __launch_bounds__(256) void init_kernel(v4* __restrict__ states4) {
    int idx = blockIdx.x * 256 + threadIdx.x;        // 0 .. T*R/4-1
    const float s = __uint_as_float(SENTINEL);
    v4 v = (idx < RSIZE / 4) ? (v4){0.f, 0.f, 0.f, 0.f} : (v4){s, s, s, s};
    states4[idx] = v;
}

__device__ __forceinline__ float dot4(v4 a, v4 b) {
    float s = a.x * b.x;
    s = fmaf(a.y, b.y, s);
    s = fmaf(a.z, b.z, s);
    s = fmaf(a.w, b.w, s);
    return s;
}

// 8 rows/wave, 256 independent 64-thread blocks (1 per CU). No LDS, no
// barriers. Poll traffic = 256 waves x 8KB/round = 2MB/round (round-1's
// proven-safe level; round-2's 8MB/round saturated the LLC and regressed).
// Publish = one 32B coalesced store from lanes 0-7 -> 2 writers/cacheline
// (was 8), shrinking the line-ownership ping-pong tail per step.

__global__ __launch_bounds__(64, 1) void reservoir_kernel(
    const float* __restrict__ W,        // [R][R]
    const float* __restrict__ Win,      // [R][8]
    const float* __restrict__ Wfb,      // [R][4]
    const float* __restrict__ inputs,   // [T][8]
    const float* __restrict__ outputs,  // [T][4]
    const float* __restrict__ noise,    // [T][R]
    float* __restrict__ states)         // [T][R]
{
    const int lane = threadIdx.x;       // block == 1 wave
    const int wid  = blockIdx.x;        // 0..255
    const int r0   = wid * 8;           // this wave's 8 rows

    // ---- W into NAMED registers: 8 rows x 32 cols/lane, cols = j*512 + lane*8 + k ----
    #define DECLW(r) v4 w##r##00, w##r##01, w##r##10, w##r##11, \
                        w##r##20, w##r##21, w##r##30, w##r##31
    DECLW(0); DECLW(1); DECLW(2); DECLW(3);
    DECLW(4); DECLW(5); DECLW(6); DECLW(7);

    #define LOADW(r) do { \
        const float* p = W + (size_t)(r0 + r) * RSIZE + lane * 8;        \
        w##r##00 = *(const v4*)(p +    0); w##r##01 = *(const v4*)(p +    4); \
        w##r##10 = *(const v4*)(p +  512); w##r##11 = *(const v4*)(p +  516); \
        w##r##20 = *(const v4*)(p + 1024); w##r##21 = *(const v4*)(p + 1028); \
        w##r##30 = *(const v4*)(p + 1536); w##r##31 = *(const v4*)(p + 1540); \
    } while (0)
    LOADW(0); LOADW(1); LOADW(2); LOADW(3);
    LOADW(4); LOADW(5); LOADW(6); LOADW(7);

    // Pin: opaque to the optimizer so the loads can't sink into the time loop.
    #define PINW(r) do { \
        asm volatile("" : "+v"(w##r##00), "+v"(w##r##01), "+v"(w##r##10), "+v"(w##r##11)); \
        asm volatile("" : "+v"(w##r##20), "+v"(w##r##21), "+v"(w##r##30), "+v"(w##r##31)); \
    } while (0)
    PINW(0); PINW(1); PINW(2); PINW(3);
    PINW(4); PINW(5); PINW(6); PINW(7);

    // ---- lanes 0..7 keep Win/Wfb for their row ----
    float win[N_IN] = {0}, wfb[N_OUT] = {0};
    if (lane < 8) {
        const int r = r0 + lane;
        #pragma unroll
        for (int j = 0; j < N_IN; ++j)  win[j] = Win[r * N_IN + j];
        #pragma unroll
        for (int k = 0; k < N_OUT; ++k) wfb[k] = Wfb[r * N_OUT + k];
    }

    const int li = lane * 2;   // v4 index of this lane's pair within a 512-col block

    for (int n = 1; n < T_STEPS; ++n) {
        // ---- pre-poll: terms that don't depend on x_{n-1} (overlap poll wait) ----
        float pre = 0.0f, nz = 0.0f;
        if (lane < 8) {
            const int r = r0 + lane;
            nz = noise[(size_t)n * RSIZE + r];
            #pragma unroll
            for (int j = 0; j < N_IN; ++j)  pre = fmaf(win[j], inputs[n * N_IN + j], pre);
            #pragma unroll
            for (int k = 0; k < N_OUT; ++k) pre = fmaf(wfb[k], outputs[(n - 1) * N_OUT + k], pre);
        }

        // ---- poll ALL 32 cols this lane needs (8x volatile dwordx4) ----
        const volatile v4* row = (const volatile v4*)(states + (size_t)(n - 1) * RSIZE);
        v4 x00, x01, x10, x11, x20, x21, x30, x31;
        #define OKV(v) ((__float_as_uint(v.x) != SENTINEL) & \
                        (__float_as_uint(v.y) != SENTINEL) & \
                        (__float_as_uint(v.z) != SENTINEL) & \
                        (__float_as_uint(v.w) != SENTINEL))
        for (;;) {
            x00 = row[  0 + li]; x01 = row[  0 + li + 1];
            x10 = row[128 + li]; x11 = row[128 + li + 1];
            x20 = row[256 + li]; x21 = row[256 + li + 1];
            x30 = row[384 + li]; x31 = row[384 + li + 1];
            bool ok = OKV(x00) & OKV(x01) & OKV(x10) & OKV(x11) &
                      OKV(x20) & OKV(x21) & OKV(x30) & OKV(x31);
            if (ok) break;
            __builtin_amdgcn_s_sleep(1);
        }
        #undef OKV

        // ---- 8-row dot, straight from polled registers (same per-row order) ----
        float a0, a1, a2, a3, a4, a5, a6, a7;
        #define DOTR(r, acc) do { \
            acc  = dot4(w##r##00, x00) + dot4(w##r##01, x01); \
            acc += dot4(w##r##10, x10) + dot4(w##r##11, x11); \
            acc += dot4(w##r##20, x20) + dot4(w##r##21, x21); \
            acc += dot4(w##r##30, x30) + dot4(w##r##31, x31); \
        } while (0)
        DOTR(0, a0); DOTR(1, a1); DOTR(2, a2); DOTR(3, a3);
        DOTR(4, a4); DOTR(5, a5); DOTR(6, a6); DOTR(7, a7);

        // ---- merged xor-tree reduction: 10 shfl+add; lane l<8 ends with
        //      row r0+l's full sum. Same balanced xor tree per row as 8
        //      independent butterflies (fp add commutes bitwise) -> bit-identical.
        const bool o1 = lane & 1, o2 = lane & 2, o4 = lane & 4;
        float c0 = (o1 ? a1 : a0) + __shfl_xor(o1 ? a0 : a1, 1, 64);
        float c1 = (o1 ? a3 : a2) + __shfl_xor(o1 ? a2 : a3, 1, 64);
        float c2 = (o1 ? a5 : a4) + __shfl_xor(o1 ? a4 : a5, 1, 64);
        float c3 = (o1 ? a7 : a6) + __shfl_xor(o1 ? a6 : a7, 1, 64);
        float d0 = (o2 ? c1 : c0) + __shfl_xor(o2 ? c0 : c1, 2, 64);
        float d1 = (o2 ? c3 : c2) + __shfl_xor(o2 ? c2 : c3, 2, 64);
        float e  = (o4 ? d1 : d0) + __shfl_xor(o4 ? d0 : d1, 4, 64);
        e += __shfl_xor(e,  8, 64);
        e += __shfl_xor(e, 16, 64);
        e += __shfl_xor(e, 32, 64);

        // ---- epilogue + publish: lanes 0..7, one coalesced 32B store ----
        if (lane < 8) {
            float s  = e + pre;
            float xn = tanhf(s) + nz;
            *(volatile float*)(states + (size_t)n * RSIZE + r0 + lane) = xn;
        }
        __builtin_amdgcn_s_waitcnt(0);   // flush publish promptly
    }
    #undef DECLW
    #undef LOADW
    #undef PINW
    #undef DOTR
}

__global__ __launch_bounds__(256) void readout_kernel(
    const float* __restrict__ states,   // [T][R]
    const float* __restrict__ inputs,   // [T][8]
    const float* __restrict__ lin_w,    // [4][2056]
    const float* __restrict__ lin_b,    // [4]
    float* __restrict__ out)            // [T][4]
{
    const int ti   = blockIdx.x;
    const int tid  = threadIdx.x;
    const int lane = tid & 63;
    const int wave = tid >> 6;
    const int c0   = tid * 8;

    const float* xp = states + (size_t)ti * RSIZE + c0;
    v4 xa = *(const v4*)xp;
    v4 xb = *(const v4*)(xp + 4);

    float acc[N_OUT];
    #pragma unroll
    for (int o = 0; o < N_OUT; ++o) {
        const float* lp = lin_w + (size_t)o * LIN_STRIDE + c0;
        v4 la = *(const v4*)lp;
        v4 lb = *(const v4*)(lp + 4);
        acc[o] = dot4(la, xa) + dot4(lb, xb);
    }

    #pragma unroll
    for (int m = 1; m < 64; m <<= 1) {
        #pragma unroll
        for (int o = 0; o < N_OUT; ++o) acc[o] += __shfl_xor(acc[o], m, 64);
    }

    __shared__ float red[4][N_OUT];
    if (lane == 0) {
        #pragma unroll
        for (int o = 0; o < N_OUT; ++o) red[wave][o] = acc[o];
    }
    __syncthreads();

    if (tid < N_OUT) {
        float s = red[0][tid] + red[1][tid] + red[2][tid] + red[3][tid] + lin_b[tid];
        if (ti > 0) {   // states_u row 0 is zero
            #pragma unroll
            for (int j = 0; j < N_IN; ++j)
                s = fmaf(lin_w[(size_t)tid * LIN_STRIDE + RSIZE + j],
                         inputs[ti * N_IN + j], s);
        }
        out[ti * N_OUT + tid] = s;
    }
}

extern "C" void kernel_launch(void* const* d_in, const int* in_sizes, int n_in,
                              void* d_out, int out_size, void* d_ws, size_t ws_size,
                              hipStream_t stream) {
    const float* inputs  = (const float*)d_in[0];
    const float* outputs = (const float*)d_in[1];
    const float* W       = (const float*)d_in[2];
    const float* Win     = (const float*)d_in[3];
    const float* Wfb     = (const float*)d_in[4];
    const float* lin_w   = (const float*)d_in[5];
    const float* lin_b   = (const float*)d_in[6];
    const float* noise   = (const float*)d_in[7];
    float* out = (float*)d_out;

    float* states = (float*)d_ws;

    hipLaunchKernelGGL(init_kernel, dim3((T_STEPS * RSIZE / 4) / 256), dim3(256), 0,
                       stream, (v4*)states);
    hipLaunchKernelGGL(reservoir_kernel, dim3(256), dim3(64), 0, stream,
                       W, Win, Wfb, inputs, outputs, noise, states);
    hipLaunchKernelGGL(readout_kernel, dim3(T_STEPS), dim3(256), 0, stream,
                       states, inputs, lin_w, lin_b, out);
}

// Round 4
// 10135.297 us; speedup vs baseline: 1.6445x; 1.5992x over previous
//
#include <hip/hip_runtime.h>

#define T_STEPS 4096
#define RSIZE   2048
#define N_IN    8
#define N_OUT   4
#define LIN_STRIDE  (RSIZE + N_IN)   // 2056 — readout weight row stride
#define SENTINEL    0x7FC00000u      // qNaN bits; recurrence never produces it

typedef float v4 __attribute__((ext_vector_type(4)));

// d_ws: states [T][R] float. Row 0 zeros, rows 1.. sentinel. Data IS the flag.

__global__ __launch_bounds__(256) void init_kernel(v4* __restrict__ states4) {
    int idx = blockIdx.x * 256 + threadIdx.x;        // 0 .. T*R/4-1
    const float s = __uint_as_float(SENTINEL);
    v4 v = (idx < RSIZE / 4) ? (v4){0.f, 0.f, 0.f, 0.f} : (v4){s, s, s, s};
    states4[idx] = v;
}

__device__ __forceinline__ float dot4(v4 a, v4 b) {
    float s = a.x * b.x;
    s = fmaf(a.y, b.y, s);
    s = fmaf(a.z, b.z, s);
    s = fmaf(a.w, b.w, s);
    return s;
}

// R1 structure (proven best: slice-poll + LDS share + 1 barrier) with the
// serial chain shaved:
//  - 4 rows/wave, 2 waves/WG, 256 WGs (1/CU): publish = 512 coalesced 16B
//    stores (was 1024x8B), straggler pool halved.
//  - each wave polls only its 4KB half-row (4 dwordx4) -> R1-class detection.
//  - per-step W loads issued via opaque pointer BEFORE the poll: the 64KB/CU
//    L2 traffic completes during wait-for-last-publisher slack, off the
//    post-detection path. Live range = one iteration -> no spill pressure.
//  - no publisher s_waitcnt flush (stalled the wave ~LLC ack for nothing),
//    no s_sleep (tighter detection granularity).

__global__ __launch_bounds__(128, 1) void reservoir_kernel(
    const float* __restrict__ W,        // [R][R]
    const float* __restrict__ Win,      // [R][8]
    const float* __restrict__ Wfb,      // [R][4]
    const float* __restrict__ inputs,   // [T][8]
    const float* __restrict__ outputs,  // [T][4]
    const float* __restrict__ noise,    // [T][R]
    float* __restrict__ states)         // [T][R]
{
    const int t    = threadIdx.x;
    const int lane = t & 63;
    const int wv   = t >> 6;            // wave in WG: 0..1
    const int g    = blockIdx.x;        // 0..255
    const int r0   = g * 8 + wv * 4;    // this wave's 4 rows

    // ---- lanes 0..3 keep Win/Wfb for their row ----
    float win[N_IN] = {0}, wfb[N_OUT] = {0};
    if (lane < 4) {
        const int r = r0 + lane;
        #pragma unroll
        for (int j = 0; j < N_IN; ++j)  win[j] = Win[r * N_IN + j];
        #pragma unroll
        for (int k = 0; k < N_OUT; ++k) wfb[k] = Wfb[r * N_OUT + k];
    }

    // parity double-buffered x in LDS (bank-swizzled, R1-v2 mapping)
    __shared__ v4 xsh[2][RSIZE / 4];    // 16 KB
    const int li = lane * 2;                    // v4-pair base within a 128-v4 block
    const int sx = li ^ ((li >> 3) & 7);        // swizzled position (sx^1 = partner)
    const int b0 = (2 * wv)     * 128;          // this wave's two fill blocks (v4 idx)
    const int b1 = (2 * wv + 1) * 128;

    const float* wbase = W + (size_t)r0 * RSIZE + lane * 8;

    for (int n = 1; n < T_STEPS; ++n) {
        // ---- per-step W loads: opaque pointer (blocks LICM -> no whole-loop
        //      live range / spills), pinned so they issue & complete HERE,
        //      hidden under the wait for the last publisher. ----
        const float* wq = wbase;
        asm volatile("" : "+v"(wq));
        #define LW(r, j, k) (*(const v4*)(wq + (size_t)(r) * RSIZE + (j) * 512 + (k) * 4))
        v4 w000 = LW(0,0,0), w001 = LW(0,0,1), w010 = LW(0,1,0), w011 = LW(0,1,1);
        v4 w020 = LW(0,2,0), w021 = LW(0,2,1), w030 = LW(0,3,0), w031 = LW(0,3,1);
        v4 w100 = LW(1,0,0), w101 = LW(1,0,1), w110 = LW(1,1,0), w111 = LW(1,1,1);
        v4 w120 = LW(1,2,0), w121 = LW(1,2,1), w130 = LW(1,3,0), w131 = LW(1,3,1);
        v4 w200 = LW(2,0,0), w201 = LW(2,0,1), w210 = LW(2,1,0), w211 = LW(2,1,1);
        v4 w220 = LW(2,2,0), w221 = LW(2,2,1), w230 = LW(2,3,0), w231 = LW(2,3,1);
        v4 w300 = LW(3,0,0), w301 = LW(3,0,1), w310 = LW(3,1,0), w311 = LW(3,1,1);
        v4 w320 = LW(3,2,0), w321 = LW(3,2,1), w330 = LW(3,3,0), w331 = LW(3,3,1);
        #undef LW
        asm volatile("" : "+v"(w000), "+v"(w001), "+v"(w010), "+v"(w011));
        asm volatile("" : "+v"(w020), "+v"(w021), "+v"(w030), "+v"(w031));
        asm volatile("" : "+v"(w100), "+v"(w101), "+v"(w110), "+v"(w111));
        asm volatile("" : "+v"(w120), "+v"(w121), "+v"(w130), "+v"(w131));
        asm volatile("" : "+v"(w200), "+v"(w201), "+v"(w210), "+v"(w211));
        asm volatile("" : "+v"(w220), "+v"(w221), "+v"(w230), "+v"(w231));
        asm volatile("" : "+v"(w300), "+v"(w301), "+v"(w310), "+v"(w311));
        asm volatile("" : "+v"(w320), "+v"(w321), "+v"(w330), "+v"(w331));

        // ---- pre-poll: terms that don't depend on x_{n-1} ----
        float pre = 0.0f, nz = 0.0f;
        if (lane < 4) {
            const int r = r0 + lane;
            nz = noise[(size_t)n * RSIZE + r];
            #pragma unroll
            for (int j = 0; j < N_IN; ++j)  pre = fmaf(win[j], inputs[n * N_IN + j], pre);
            #pragma unroll
            for (int k = 0; k < N_OUT; ++k) pre = fmaf(wfb[k], outputs[(n - 1) * N_OUT + k], pre);
        }

        // ---- poll my half-row: 4 x volatile dwordx4 (blocks 2wv, 2wv+1) ----
        const volatile v4* row = (const volatile v4*)(states + (size_t)(n - 1) * RSIZE);
        v4 xa0, xa1, xb0, xb1;
        #define OKV(v) ((__float_as_uint(v.x) != SENTINEL) & \
                        (__float_as_uint(v.y) != SENTINEL) & \
                        (__float_as_uint(v.z) != SENTINEL) & \
                        (__float_as_uint(v.w) != SENTINEL))
        for (;;) {
            xa0 = row[b0 + li]; xa1 = row[b0 + li + 1];
            xb0 = row[b1 + li]; xb1 = row[b1 + li + 1];
            if (OKV(xa0) & OKV(xa1) & OKV(xb0) & OKV(xb1)) break;
        }
        #undef OKV

        const int p = (n - 1) & 1;
        xsh[p][b0 + sx]       = xa0;
        xsh[p][b0 + (sx ^ 1)] = xa1;
        xsh[p][b1 + sx]       = xb0;
        xsh[p][b1 + (sx ^ 1)] = xb1;
        __syncthreads();

        // ---- 4-row dot over all 2048 cols from LDS (same per-row order as R1) ----
        float a0 = 0.0f, a1 = 0.0f, a2 = 0.0f, a3 = 0.0f;
        {
            v4 x0 = xsh[p][  0 + sx], x1 = xsh[p][  0 + (sx ^ 1)];
            a0 += dot4(w000, x0) + dot4(w001, x1);
            a1 += dot4(w100, x0) + dot4(w101, x1);
            a2 += dot4(w200, x0) + dot4(w201, x1);
            a3 += dot4(w300, x0) + dot4(w301, x1);
        }
        {
            v4 x0 = xsh[p][128 + sx], x1 = xsh[p][128 + (sx ^ 1)];
            a0 += dot4(w010, x0) + dot4(w011, x1);
            a1 += dot4(w110, x0) + dot4(w111, x1);
            a2 += dot4(w210, x0) + dot4(w211, x1);
            a3 += dot4(w310, x0) + dot4(w311, x1);
        }
        {
            v4 x0 = xsh[p][256 + sx], x1 = xsh[p][256 + (sx ^ 1)];
            a0 += dot4(w020, x0) + dot4(w021, x1);
            a1 += dot4(w120, x0) + dot4(w121, x1);
            a2 += dot4(w220, x0) + dot4(w221, x1);
            a3 += dot4(w320, x0) + dot4(w321, x1);
        }
        {
            v4 x0 = xsh[p][384 + sx], x1 = xsh[p][384 + (sx ^ 1)];
            a0 += dot4(w030, x0) + dot4(w031, x1);
            a1 += dot4(w130, x0) + dot4(w131, x1);
            a2 += dot4(w230, x0) + dot4(w231, x1);
            a3 += dot4(w330, x0) + dot4(w331, x1);
        }

        // ---- merged 4-row xor-tree: 7 shfl+add; lane l<4 ends with row
        //      r0+l's sum via the SAME balanced 64-leaf tree as the full
        //      butterfly (bit-identical; validated pattern from R3). ----
        const bool o1 = lane & 1, o2 = lane & 2;
        float c0 = (o1 ? a1 : a0) + __shfl_xor(o1 ? a0 : a1, 1, 64);
        float c1 = (o1 ? a3 : a2) + __shfl_xor(o1 ? a2 : a3, 1, 64);
        float e  = (o2 ? c1 : c0) + __shfl_xor(o2 ? c0 : c1, 2, 64);
        e += __shfl_xor(e,  4, 64);
        e += __shfl_xor(e,  8, 64);
        e += __shfl_xor(e, 16, 64);
        e += __shfl_xor(e, 32, 64);

        // ---- epilogue + publish: lanes 0..3, one coalesced 16B store.
        //      No trailing waitcnt: the store is already issued; waiting for
        //      its ack only stalls this wave, not visibility. ----
        if (lane < 4) {
            float s  = e + pre;
            float xn = tanhf(s) + nz;
            *(volatile float*)(states + (size_t)n * RSIZE + r0 + lane) = xn;
        }
    }
}

__global__ __launch_bounds__(256) void readout_kernel(
    const float* __restrict__ states,   // [T][R]
    const float* __restrict__ inputs,   // [T][8]
    const float* __restrict__ lin_w,    // [4][2056]
    const float* __restrict__ lin_b,    // [4]
    float* __restrict__ out)            // [T][4]
{
    const int ti   = blockIdx.x;
    const int tid  = threadIdx.x;
    const int lane = tid & 63;
    const int wave = tid >> 6;
    const int c0   = tid * 8;

    const float* xp = states + (size_t)ti * RSIZE + c0;
    v4 xa = *(const v4*)xp;
    v4 xb = *(const v4*)(xp + 4);

    float acc[N_OUT];
    #pragma unroll
    for (int o = 0; o < N_OUT; ++o) {
        const float* lp = lin_w + (size_t)o * LIN_STRIDE + c0;
        v4 la = *(const v4*)lp;
        v4 lb = *(const v4*)(lp + 4);
        acc[o] = dot4(la, xa) + dot4(lb, xb);
    }

    #pragma unroll
    for (int m = 1; m < 64; m <<= 1) {
        #pragma unroll
        for (int o = 0; o < N_OUT; ++o) acc[o] += __shfl_xor(acc[o], m, 64);
    }

    __shared__ float red[4][N_OUT];
    if (lane == 0) {
        #pragma unroll
        for (int o = 0; o < N_OUT; ++o) red[wave][o] = acc[o];
    }
    __syncthreads();

    if (tid < N_OUT) {
        float s = red[0][tid] + red[1][tid] + red[2][tid] + red[3][tid] + lin_b[tid];
        if (ti > 0) {   // states_u row 0 is zero
            #pragma unroll
            for (int j = 0; j < N_IN; ++j)
                s = fmaf(lin_w[(size_t)tid * LIN_STRIDE + RSIZE + j],
                         inputs[ti * N_IN + j], s);
        }
        out[ti * N_OUT + tid] = s;
    }
}

extern "C" void kernel_launch(void* const* d_in, const int* in_sizes, int n_in,
                              void* d_out, int out_size, void* d_ws, size_t ws_size,
                              hipStream_t stream) {
    const float* inputs  = (const float*)d_in[0];
    const float* outputs = (const float*)d_in[1];
    const float* W       = (const float*)d_in[2];
    const float* Win     = (const float*)d_in[3];
    const float* Wfb     = (const float*)d_in[4];
    const float* lin_w   = (const float*)d_in[5];
    const float* lin_b   = (const float*)d_in[6];
    const float* noise   = (const float*)d_in[7];
    float* out = (float*)d_out;

    float* states = (float*)d_ws;

    hipLaunchKernelGGL(init_kernel, dim3((T_STEPS * RSIZE / 4) / 256), dim3(256), 0,
                       stream, (v4*)states);
    hipLaunchKernelGGL(reservoir_kernel, dim3(256), dim3(128), 0, stream,
                       W, Win, Wfb, inputs, outputs, noise, states);
    hipLaunchKernelGGL(readout_kernel, dim3(T_STEPS), dim3(256), 0, stream,
                       states, inputs, lin_w, lin_b, out);
}

// Round 5
// 7497.816 us; speedup vs baseline: 2.2230x; 1.3518x over previous
//
#include <hip/hip_runtime.h>

#define T_STEPS 4096
#define RSIZE   2048
#define N_IN    8
#define N_OUT   4
#define NWG     256
#define NT      256                  // 4 waves per WG — R1's proven detection structure
#define LIN_STRIDE  (RSIZE + N_IN)   // 2056 — readout weight row stride
#define SENTINEL    0x7FC00000u      // qNaN bits; recurrence never produces it

typedef float v4 __attribute__((ext_vector_type(4)));
typedef float v2 __attribute__((ext_vector_type(2)));

// d_ws: states [T][R] float. Row 0 zeros, rows 1.. sentinel. Data IS the flag.

__global__ __launch_bounds__(256) void init_kernel(v4* __restrict__ states4) {
    int idx = blockIdx.x * 256 + threadIdx.x;        // 0 .. T*R/4-1
    const float s = __uint_as_float(SENTINEL);
    v4 v = (idx < RSIZE / 4) ? (v4){0.f, 0.f, 0.f, 0.f} : (v4){s, s, s, s};
    states4[idx] = v;
}

__device__ __forceinline__ float dot4(v4 a, v4 b) {
    float s = a.x * b.x;
    s = fmaf(a.y, b.y, s);
    s = fmaf(a.z, b.z, s);
    s = fmaf(a.w, b.w, s);
    return s;
}

// R1 structure (the only proven-fast one: per-wave 2KB slice poll -> LDS share
// -> 1 barrier -> full-row dot). Single change this round: W comes from LDS.
// The WG stages its 64KB W slice into LDS once, then each wave loads its 16
// W fragments into registers BEFORE the time loop and pins them. If the pins
// hold, per-step W cost is zero; if the compiler sinks the reads into the
// loop anyway, the reload is from LDS (~69 TB/s, overlappable) instead of the
// per-step L2 stream that R1 was silently paying (VGPR=60 showed W was never
// register-resident; R4 proved the L2 stream costs ~3ms when fully exposed).

__global__ __launch_bounds__(NT, 1) void reservoir_kernel(
    const float* __restrict__ W,        // [R][R]
    const float* __restrict__ Win,      // [R][8]
    const float* __restrict__ Wfb,      // [R][4]
    const float* __restrict__ inputs,   // [T][8]
    const float* __restrict__ outputs,  // [T][4]
    const float* __restrict__ noise,    // [T][R]
    float* __restrict__ states)         // [T][R]
{
    const int g    = blockIdx.x;
    const int t    = threadIdx.x;
    const int lane = t & 63;
    const int wv   = t >> 6;            // wave in WG: 0..3
    const int r0   = g * 8 + wv * 2;    // this wave's 2 global rows

    __shared__ v4 wlds[8][512];         // 64 KB: WG's 8-row W slice (swizzled)
    __shared__ v4 xsh[2][RSIZE / 4];    // 16 KB: parity double-buffered x

    // ---- prologue: stage W slice into LDS (coalesced loads, swizzled stores) ----
    {
        const v4* Wv = (const v4*)(W + (size_t)g * 8 * RSIZE);   // [8*512] v4
        #pragma unroll
        for (int it = 0; it < 16; ++it) {
            int gi  = it * 256 + t;                 // 0..4095
            int row = gi >> 9;
            int i   = gi & 511;
            int pos = (i & ~127) | ((i & 127) ^ ((i >> 3) & 7));
            wlds[row][pos] = Wv[gi];
        }
    }
    __syncthreads();

    const int li    = lane * 2;                  // v4-pair base within a 128-v4 block
    const int sx    = li ^ ((li >> 3) & 7);      // swizzled position (sx^1 = partner)
    const int fbase = wv * 128;                  // this wave's fill block (v4 idx)
    const int fillc = wv * 512 + lane * 8;       // col this lane polls/fills
    const int lr    = wv * 2;                    // WG-local row of this wave

    // ---- W into registers from LDS, once, pinned before the loop ----
    v4 w000 = wlds[lr][  0 + sx], w001 = wlds[lr][  0 + (sx ^ 1)];
    v4 w010 = wlds[lr][128 + sx], w011 = wlds[lr][128 + (sx ^ 1)];
    v4 w020 = wlds[lr][256 + sx], w021 = wlds[lr][256 + (sx ^ 1)];
    v4 w030 = wlds[lr][384 + sx], w031 = wlds[lr][384 + (sx ^ 1)];
    v4 w100 = wlds[lr + 1][  0 + sx], w101 = wlds[lr + 1][  0 + (sx ^ 1)];
    v4 w110 = wlds[lr + 1][128 + sx], w111 = wlds[lr + 1][128 + (sx ^ 1)];
    v4 w120 = wlds[lr + 1][256 + sx], w121 = wlds[lr + 1][256 + (sx ^ 1)];
    v4 w130 = wlds[lr + 1][384 + sx], w131 = wlds[lr + 1][384 + (sx ^ 1)];
    asm volatile("" : "+v"(w000), "+v"(w001), "+v"(w010), "+v"(w011));
    asm volatile("" : "+v"(w020), "+v"(w021), "+v"(w030), "+v"(w031));
    asm volatile("" : "+v"(w100), "+v"(w101), "+v"(w110), "+v"(w111));
    asm volatile("" : "+v"(w120), "+v"(w121), "+v"(w130), "+v"(w131));

    // ---- lanes 0,1 keep Win/Wfb for their row ----
    float win[N_IN] = {0}, wfb[N_OUT] = {0};
    if (lane < 2) {
        const int r = r0 + lane;
        #pragma unroll
        for (int j = 0; j < N_IN; ++j)  win[j] = Win[r * N_IN + j];
        #pragma unroll
        for (int k = 0; k < N_OUT; ++k) wfb[k] = Wfb[r * N_OUT + k];
    }

    for (int n = 1; n < T_STEPS; ++n) {
        // ---- pre-poll: terms that don't depend on x_{n-1} ----
        float pre = 0.0f, nz = 0.0f;
        if (lane < 2) {
            const int r = r0 + lane;
            nz = noise[(size_t)n * RSIZE + r];
            #pragma unroll
            for (int j = 0; j < N_IN; ++j)  pre = fmaf(win[j], inputs[n * N_IN + j], pre);
            #pragma unroll
            for (int k = 0; k < N_OUT; ++k) pre = fmaf(wfb[k], outputs[(n - 1) * N_OUT + k], pre);
        }

        // ---- poll my 8 contiguous cols of x_{n-1} (2x volatile dwordx4) ----
        const volatile v4* src =
            (const volatile v4*)(states + (size_t)(n - 1) * RSIZE + fillc);
        v4 a, b;
        for (;;) {
            a = src[0];
            b = src[1];
            bool ok = (__float_as_uint(a.x) != SENTINEL) &
                      (__float_as_uint(a.y) != SENTINEL) &
                      (__float_as_uint(a.z) != SENTINEL) &
                      (__float_as_uint(a.w) != SENTINEL) &
                      (__float_as_uint(b.x) != SENTINEL) &
                      (__float_as_uint(b.y) != SENTINEL) &
                      (__float_as_uint(b.z) != SENTINEL) &
                      (__float_as_uint(b.w) != SENTINEL);
            if (ok) break;
            __builtin_amdgcn_s_sleep(1);
        }

        const int p = (n - 1) & 1;
        xsh[p][fbase + sx]       = a;    // swizzled, conflict-free ds_write_b128
        xsh[p][fbase + (sx ^ 1)] = b;
        __syncthreads();

        // ---- 2-row dot over all 2048 cols; own block (j==wv) straight from
        //      the polled registers (identical values to its LDS copy). ----
        float acc0 = 0.0f, acc1 = 0.0f;
        {
            v4 x0, x1;
            if (wv == 0) { x0 = a; x1 = b; }
            else         { x0 = xsh[p][  0 + sx]; x1 = xsh[p][  0 + (sx ^ 1)]; }
            acc0 += dot4(w000, x0) + dot4(w001, x1);
            acc1 += dot4(w100, x0) + dot4(w101, x1);
        }
        {
            v4 x0, x1;
            if (wv == 1) { x0 = a; x1 = b; }
            else         { x0 = xsh[p][128 + sx]; x1 = xsh[p][128 + (sx ^ 1)]; }
            acc0 += dot4(w010, x0) + dot4(w011, x1);
            acc1 += dot4(w110, x0) + dot4(w111, x1);
        }
        {
            v4 x0, x1;
            if (wv == 2) { x0 = a; x1 = b; }
            else         { x0 = xsh[p][256 + sx]; x1 = xsh[p][256 + (sx ^ 1)]; }
            acc0 += dot4(w020, x0) + dot4(w021, x1);
            acc1 += dot4(w120, x0) + dot4(w121, x1);
        }
        {
            v4 x0, x1;
            if (wv == 3) { x0 = a; x1 = b; }
            else         { x0 = xsh[p][384 + sx]; x1 = xsh[p][384 + (sx ^ 1)]; }
            acc0 += dot4(w030, x0) + dot4(w031, x1);
            acc1 += dot4(w130, x0) + dot4(w131, x1);
        }

        // ---- 64-lane butterfly: every lane ends with both row totals ----
        #pragma unroll
        for (int m = 1; m < 64; m <<= 1) {
            acc0 += __shfl_xor(acc0, m, 64);
            acc1 += __shfl_xor(acc1, m, 64);
        }

        // ---- epilogue + publish (lanes 0,1) ----
        if (lane < 2) {
            float s  = (lane == 0 ? acc0 : acc1) + pre;
            float xn = tanhf(s) + nz;
            *(volatile float*)(states + (size_t)n * RSIZE + r0 + lane) = xn;
        }
        __builtin_amdgcn_s_waitcnt(0);   // flush publish promptly
    }
}

__global__ __launch_bounds__(256) void readout_kernel(
    const float* __restrict__ states,   // [T][R]
    const float* __restrict__ inputs,   // [T][8]
    const float* __restrict__ lin_w,    // [4][2056]
    const float* __restrict__ lin_b,    // [4]
    float* __restrict__ out)            // [T][4]
{
    const int ti   = blockIdx.x;
    const int tid  = threadIdx.x;
    const int lane = tid & 63;
    const int wave = tid >> 6;
    const int c0   = tid * 8;

    const float* xp = states + (size_t)ti * RSIZE + c0;
    v4 xa = *(const v4*)xp;
    v4 xb = *(const v4*)(xp + 4);

    float acc[N_OUT];
    #pragma unroll
    for (int o = 0; o < N_OUT; ++o) {
        const float* lp = lin_w + (size_t)o * LIN_STRIDE + c0;
        v4 la = *(const v4*)lp;
        v4 lb = *(const v4*)(lp + 4);
        acc[o] = dot4(la, xa) + dot4(lb, xb);
    }

    #pragma unroll
    for (int m = 1; m < 64; m <<= 1) {
        #pragma unroll
        for (int o = 0; o < N_OUT; ++o) acc[o] += __shfl_xor(acc[o], m, 64);
    }

    __shared__ float red[4][N_OUT];
    if (lane == 0) {
        #pragma unroll
        for (int o = 0; o < N_OUT; ++o) red[wave][o] = acc[o];
    }
    __syncthreads();

    if (tid < N_OUT) {
        float s = red[0][tid] + red[1][tid] + red[2][tid] + red[3][tid] + lin_b[tid];
        if (ti > 0) {   // states_u row 0 is zero
            #pragma unroll
            for (int j = 0; j < N_IN; ++j)
                s = fmaf(lin_w[(size_t)tid * LIN_STRIDE + RSIZE + j],
                         inputs[ti * N_IN + j], s);
        }
        out[ti * N_OUT + tid] = s;
    }
}

extern "C" void kernel_launch(void* const* d_in, const int* in_sizes, int n_in,
                              void* d_out, int out_size, void* d_ws, size_t ws_size,
                              hipStream_t stream) {
    const float* inputs  = (const float*)d_in[0];
    const float* outputs = (const float*)d_in[1];
    const float* W       = (const float*)d_in[2];
    const float* Win     = (const float*)d_in[3];
    const float* Wfb     = (const float*)d_in[4];
    const float* lin_w   = (const float*)d_in[5];
    const float* lin_b   = (const float*)d_in[6];
    const float* noise   = (const float*)d_in[7];
    float* out = (float*)d_out;

    float* states = (float*)d_ws;

    hipLaunchKernelGGL(init_kernel, dim3((T_STEPS * RSIZE / 4) / 256), dim3(256), 0,
                       stream, (v4*)states);
    hipLaunchKernelGGL(reservoir_kernel, dim3(NWG), dim3(NT), 0, stream,
                       W, Win, Wfb, inputs, outputs, noise, states);
    hipLaunchKernelGGL(readout_kernel, dim3(T_STEPS), dim3(256), 0, stream,
                       states, inputs, lin_w, lin_b, out);
}

// Round 6
// 7283.402 us; speedup vs baseline: 2.2885x; 1.0294x over previous
//
#include <hip/hip_runtime.h>

#define T_STEPS 4096
#define RSIZE   2048
#define N_IN    8
#define N_OUT   4
#define NWG     256
#define NT      256                  // 4 waves per WG — R1's proven detection structure
#define LIN_STRIDE  (RSIZE + N_IN)   // 2056 — readout weight row stride
#define SENTINEL    0x7FC00000u      // qNaN bits; recurrence never produces it

typedef float v4 __attribute__((ext_vector_type(4)));

// d_ws: states [T][R] float. Row 0 zeros, rows 1.. sentinel. Data IS the flag.

__global__ __launch_bounds__(256) void init_kernel(v4* __restrict__ states4) {
    int idx = blockIdx.x * 256 + threadIdx.x;        // 0 .. T*R/4-1
    const float s = __uint_as_float(SENTINEL);
    v4 v = (idx < RSIZE / 4) ? (v4){0.f, 0.f, 0.f, 0.f} : (v4){s, s, s, s};
    states4[idx] = v;
}

__device__ __forceinline__ float dot4(v4 a, v4 b) {
    float s = a.x * b.x;
    s = fmaf(a.y, b.y, s);
    s = fmaf(a.z, b.z, s);
    s = fmaf(a.w, b.w, s);
    return s;
}

// EXACT R1 structure (the proven-fast one: per-wave 2KB slice poll -> LDS
// share -> 1 barrier -> full-row dot). Two serial-chain shavings only:
//  (1) no post-publish s_waitcnt(0): the store is issued and will land
//      regardless; waiting for its LLC ack only delayed this wave's entry
//      into the next step. Stale reads of the target row show the sentinel
//      and retry -> safe.
//  (2) merged 2-row xor-tree reduction: 6 dependent shfl+add instead of 12.
//      Stage 1 pairs row0/row1 across lane parity (even lanes carry row0,
//      odd carry row1); stages 2..32 are plain xor-adds. Bit-identical
//      balanced tree per row (R3-validated construction); lane 0 ends with
//      row r0's total, lane 1 with row r0+1's.

__global__ __launch_bounds__(NT, 1) void reservoir_kernel(
    const float* __restrict__ W,        // [R][R]
    const float* __restrict__ Win,      // [R][8]
    const float* __restrict__ Wfb,      // [R][4]
    const float* __restrict__ inputs,   // [T][8]
    const float* __restrict__ outputs,  // [T][4]
    const float* __restrict__ noise,    // [T][R]
    float* __restrict__ states)         // [T][R]
{
    const int g    = blockIdx.x;
    const int t    = threadIdx.x;
    const int lane = t & 63;
    const int wv   = t >> 6;            // wave in WG: 0..3
    const int wid  = g * 4 + wv;        // global wave: 0..1023
    const int r0   = wid * 2;           // this wave's 2 rows

    // ---- W into NAMED registers: 2 rows x 32 cols/lane, cols = j*512 + lane*8 + k ----
    const float* wr0 = W + (size_t)r0 * RSIZE + lane * 8;
    const float* wr1 = wr0 + RSIZE;
    v4 w000 = *(const v4*)(wr0 +    0), w001 = *(const v4*)(wr0 +    4);
    v4 w010 = *(const v4*)(wr0 +  512), w011 = *(const v4*)(wr0 +  516);
    v4 w020 = *(const v4*)(wr0 + 1024), w021 = *(const v4*)(wr0 + 1028);
    v4 w030 = *(const v4*)(wr0 + 1536), w031 = *(const v4*)(wr0 + 1540);
    v4 w100 = *(const v4*)(wr1 +    0), w101 = *(const v4*)(wr1 +    4);
    v4 w110 = *(const v4*)(wr1 +  512), w111 = *(const v4*)(wr1 +  516);
    v4 w120 = *(const v4*)(wr1 + 1024), w121 = *(const v4*)(wr1 + 1028);
    v4 w130 = *(const v4*)(wr1 + 1536), w131 = *(const v4*)(wr1 + 1540);
    asm volatile("" : "+v"(w000), "+v"(w001), "+v"(w010), "+v"(w011));
    asm volatile("" : "+v"(w020), "+v"(w021), "+v"(w030), "+v"(w031));
    asm volatile("" : "+v"(w100), "+v"(w101), "+v"(w110), "+v"(w111));
    asm volatile("" : "+v"(w120), "+v"(w121), "+v"(w130), "+v"(w131));

    // ---- lanes 0,1 keep Win/Wfb for their row ----
    float win[N_IN] = {0}, wfb[N_OUT] = {0};
    if (lane < 2) {
        const int r = r0 + lane;
        #pragma unroll
        for (int j = 0; j < N_IN; ++j)  win[j] = Win[r * N_IN + j];
        #pragma unroll
        for (int k = 0; k < N_OUT; ++k) wfb[k] = Wfb[r * N_OUT + k];
    }

    // parity double-buffered x in LDS (bank-swizzled)
    __shared__ v4 xsh[2][RSIZE / 4];    // 16 KB
    const int e     = lane * 2;                  // v4-pair base within a 128-v4 block
    const int sx    = e ^ ((e >> 3) & 7);        // swizzled position (sx^1 = partner)
    const int fillc = wv * 512 + lane * 8;       // col this lane polls/fills
    const int fbase = wv * 128;                  // v4-index base of this wave's block

    for (int n = 1; n < T_STEPS; ++n) {
        // ---- pre-poll: terms that don't depend on x_{n-1} ----
        float pre = 0.0f, nz = 0.0f;
        if (lane < 2) {
            const int r = r0 + lane;
            nz = noise[(size_t)n * RSIZE + r];
            #pragma unroll
            for (int j = 0; j < N_IN; ++j)  pre = fmaf(win[j], inputs[n * N_IN + j], pre);
            #pragma unroll
            for (int k = 0; k < N_OUT; ++k) pre = fmaf(wfb[k], outputs[(n - 1) * N_OUT + k], pre);
        }

        // ---- poll my 8 contiguous cols of x_{n-1} (2x volatile dwordx4) ----
        const volatile v4* src =
            (const volatile v4*)(states + (size_t)(n - 1) * RSIZE + fillc);
        v4 a, b;
        for (;;) {
            a = src[0];
            b = src[1];
            bool ok = (__float_as_uint(a.x) != SENTINEL) &
                      (__float_as_uint(a.y) != SENTINEL) &
                      (__float_as_uint(a.z) != SENTINEL) &
                      (__float_as_uint(a.w) != SENTINEL) &
                      (__float_as_uint(b.x) != SENTINEL) &
                      (__float_as_uint(b.y) != SENTINEL) &
                      (__float_as_uint(b.z) != SENTINEL) &
                      (__float_as_uint(b.w) != SENTINEL);
            if (ok) break;
            __builtin_amdgcn_s_sleep(1);
        }

        const int p = (n - 1) & 1;
        xsh[p][fbase + sx]       = a;    // swizzled ds_write_b128
        xsh[p][fbase + (sx ^ 1)] = b;
        __syncthreads();

        // ---- 2-row dot over all 2048 cols from LDS ----
        float acc0 = 0.0f, acc1 = 0.0f;
        {
            v4 x0 = xsh[p][  0 + sx], x1 = xsh[p][  0 + (sx ^ 1)];
            acc0 += dot4(w000, x0) + dot4(w001, x1);
            acc1 += dot4(w100, x0) + dot4(w101, x1);
        }
        {
            v4 x0 = xsh[p][128 + sx], x1 = xsh[p][128 + (sx ^ 1)];
            acc0 += dot4(w010, x0) + dot4(w011, x1);
            acc1 += dot4(w110, x0) + dot4(w111, x1);
        }
        {
            v4 x0 = xsh[p][256 + sx], x1 = xsh[p][256 + (sx ^ 1)];
            acc0 += dot4(w020, x0) + dot4(w021, x1);
            acc1 += dot4(w120, x0) + dot4(w121, x1);
        }
        {
            v4 x0 = xsh[p][384 + sx], x1 = xsh[p][384 + (sx ^ 1)];
            acc0 += dot4(w030, x0) + dot4(w031, x1);
            acc1 += dot4(w130, x0) + dot4(w131, x1);
        }

        // ---- merged 2-row xor-tree: 6 dependent shfl+add (was 12).
        //      Even lanes carry row0's tree, odd lanes row1's; identical
        //      balanced grouping per row as the double butterfly -> bit-exact.
        const bool o1 = lane & 1;
        float c = (o1 ? acc1 : acc0) + __shfl_xor(o1 ? acc0 : acc1, 1, 64);
        c += __shfl_xor(c,  2, 64);
        c += __shfl_xor(c,  4, 64);
        c += __shfl_xor(c,  8, 64);
        c += __shfl_xor(c, 16, 64);
        c += __shfl_xor(c, 32, 64);
        // lane 0 (even): row r0 total; lane 1 (odd): row r0+1 total.

        // ---- epilogue + publish (lanes 0,1). No ack wait: the store is
        //      issued; waiting for the LLC ack only delays our next step. ----
        if (lane < 2) {
            float s  = c + pre;
            float xn = tanhf(s) + nz;
            *(volatile float*)(states + (size_t)n * RSIZE + r0 + lane) = xn;
        }
    }
}

__global__ __launch_bounds__(256) void readout_kernel(
    const float* __restrict__ states,   // [T][R]
    const float* __restrict__ inputs,   // [T][8]
    const float* __restrict__ lin_w,    // [4][2056]
    const float* __restrict__ lin_b,    // [4]
    float* __restrict__ out)            // [T][4]
{
    const int ti   = blockIdx.x;
    const int tid  = threadIdx.x;
    const int lane = tid & 63;
    const int wave = tid >> 6;
    const int c0   = tid * 8;

    const float* xp = states + (size_t)ti * RSIZE + c0;
    v4 xa = *(const v4*)xp;
    v4 xb = *(const v4*)(xp + 4);

    float acc[N_OUT];
    #pragma unroll
    for (int o = 0; o < N_OUT; ++o) {
        const float* lp = lin_w + (size_t)o * LIN_STRIDE + c0;
        v4 la = *(const v4*)lp;
        v4 lb = *(const v4*)(lp + 4);
        acc[o] = dot4(la, xa) + dot4(lb, xb);
    }

    #pragma unroll
    for (int m = 1; m < 64; m <<= 1) {
        #pragma unroll
        for (int o = 0; o < N_OUT; ++o) acc[o] += __shfl_xor(acc[o], m, 64);
    }

    __shared__ float red[4][N_OUT];
    if (lane == 0) {
        #pragma unroll
        for (int o = 0; o < N_OUT; ++o) red[wave][o] = acc[o];
    }
    __syncthreads();

    if (tid < N_OUT) {
        float s = red[0][tid] + red[1][tid] + red[2][tid] + red[3][tid] + lin_b[tid];
        if (ti > 0) {   // states_u row 0 is zero
            #pragma unroll
            for (int j = 0; j < N_IN; ++j)
                s = fmaf(lin_w[(size_t)tid * LIN_STRIDE + RSIZE + j],
                         inputs[ti * N_IN + j], s);
        }
        out[ti * N_OUT + tid] = s;
    }
}

extern "C" void kernel_launch(void* const* d_in, const int* in_sizes, int n_in,
                              void* d_out, int out_size, void* d_ws, size_t ws_size,
                              hipStream_t stream) {
    const float* inputs  = (const float*)d_in[0];
    const float* outputs = (const float*)d_in[1];
    const float* W       = (const float*)d_in[2];
    const float* Win     = (const float*)d_in[3];
    const float* Wfb     = (const float*)d_in[4];
    const float* lin_w   = (const float*)d_in[5];
    const float* lin_b   = (const float*)d_in[6];
    const float* noise   = (const float*)d_in[7];
    float* out = (float*)d_out;

    float* states = (float*)d_ws;

    hipLaunchKernelGGL(init_kernel, dim3((T_STEPS * RSIZE / 4) / 256), dim3(256), 0,
                       stream, (v4*)states);
    hipLaunchKernelGGL(reservoir_kernel, dim3(NWG), dim3(NT), 0, stream,
                       W, Win, Wfb, inputs, outputs, noise, states);
    hipLaunchKernelGGL(readout_kernel, dim3(T_STEPS), dim3(256), 0, stream,
                       states, inputs, lin_w, lin_b, out);
}